// Round 5
// baseline (508.067 us; speedup 1.0000x reference)
//
#include <hip/hip_runtime.h>
#include <hip/hip_bf16.h>
#include <hip/hip_cooperative_groups.h>
#include <stdint.h>

namespace cg = cooperative_groups;

#define NN 2048
#define BK 32

typedef __bf16 bf16;
typedef __bf16 bf16x8 __attribute__((ext_vector_type(8)));
typedef __bf16 bf16x4 __attribute__((ext_vector_type(4)));
typedef float f32x4 __attribute__((ext_vector_type(4)));

// async global->LDS, 16B per lane (LDS dest = wave-uniform base + lane*16)
__device__ __forceinline__ void async_copy16(bf16* lds, const bf16* g) {
    __builtin_amdgcn_global_load_lds(
        (const __attribute__((address_space(1))) unsigned int*)g,
        (__attribute__((address_space(3))) unsigned int*)lds,
        16, 0, 0);
}

#define WAIT_VM(n) asm volatile("s_waitcnt vmcnt(" #n ")" ::: "memory")
#define BAR()                                  \
    do {                                       \
        asm volatile("" ::: "memory");         \
        __builtin_amdgcn_s_barrier();          \
        asm volatile("" ::: "memory");         \
    } while (0)

// ---------------------------------------------------------------------------
// All-phase argument block
// ---------------------------------------------------------------------------
struct MegaArgs {
    // cast
    const float* cin[4];
    bf16*        coutT[4];
    bf16*        coutN[4];
    // phase1
    const bf16*  Abf;
    const bf16*  W1t;
    const bf16*  W2t;
    const bf16*  W3bf;
    const bf16*  W3t;
    float*       M1;
    float*       M2out;
    float*       M3;
    const float* W1;
    bf16*        M1bf;
    bf16*        B1bf;
    // gemm2
    const bf16*  At;
    float*       out;
};

// ---------------------------------------------------------------------------
// Phase A: fp32 -> bf16 transpose cast, one 64x64 tile-unit (r0 body exact,
// re-gridded: unit = wg*8+u, unit -> (z, by, bx)).
// ---------------------------------------------------------------------------
__device__ __forceinline__ void cast_phase(const MegaArgs& a, char* smemraw,
                                           int unit) {
    float* tile = (float*)smemraw;  // [64][65]
    const int z   = unit >> 10;
    const int rem = unit & 1023;
    const int bx  = (rem & 31) * 64;   // col base
    const int by  = (rem >> 5) * 64;   // row base
    const float* __restrict__ in = a.cin[z];
    bf16* __restrict__ outT      = a.coutT[z];
    bf16* __restrict__ outN      = a.coutN[z];

    const int t  = threadIdx.x;
    const int c4 = (t & 15) * 4, r0 = t >> 4;
#pragma unroll
    for (int p = 0; p < 4; ++p) {
        const int r = r0 + p * 16;
        const float4 v = *(const float4*)&in[(size_t)(by + r) * NN + bx + c4];
        tile[r * 65 + c4 + 0] = v.x; tile[r * 65 + c4 + 1] = v.y;
        tile[r * 65 + c4 + 2] = v.z; tile[r * 65 + c4 + 3] = v.w;
        if (outN) {
            bf16x4 b = {(bf16)v.x, (bf16)v.y, (bf16)v.z, (bf16)v.w};
            *(bf16x4*)&outN[(size_t)(by + r) * NN + bx + c4] = b;
        }
    }
    __syncthreads();
    const int cc8 = (t & 7) * 8, rw0 = t >> 3;
#pragma unroll
    for (int p = 0; p < 2; ++p) {
        const int rw = rw0 + p * 32;
        bf16x8 b;
#pragma unroll
        for (int i = 0; i < 8; ++i) b[i] = (bf16)tile[(cc8 + i) * 65 + rw];
        *(bf16x8*)&outT[(size_t)(bx + rw) * NN + by + cc8] = b;
    }
}

// ---------------------------------------------------------------------------
// Phase B: r0 phase1 exact (depth-2, two-barrier, static dual buffers).
// wg in [0,512): z = wg>>8, bm = (wg&15)*128, bn = ((wg>>4)&15)*128.
// ---------------------------------------------------------------------------
__device__ __forceinline__ void phase1_phase(const MegaArgs& a, char* smemraw,
                                             int wg) {
    bf16* As0 = (bf16*)smemraw;
    bf16* As1 = As0 + 4096;
    bf16* B10 = As0 + 2 * 4096;
    bf16* B11 = As0 + 3 * 4096;
    bf16* B20 = As0 + 4 * 4096;
    bf16* B21 = As0 + 5 * 4096;

    const int t  = threadIdx.x;
    const int bm = (wg & 15) * 128;
    const int bn = ((wg >> 4) & 15) * 128;
    const int z  = wg >> 8;

    const int row0 = t >> 2;
    const int qp   = t & 3;
    const int col0 = ((qp ^ ((row0 >> 1) & 3)) << 3);  // XOR swizzle
    const int off0 = t * 8;

    const int wave = t >> 6;
    const int lane = t & 63;
    const int wm   = (wave >> 1) * 64;
    const int wn   = (wave & 1) * 64;
    const int lrow = lane & 15;
    const int q    = lane >> 4;
    const int qe   = (q ^ ((lrow >> 1) & 3)) << 3;

    if (z == 0) {
        const bf16* gA  = a.Abf + (size_t)(bm + row0) * NN + col0;
        const bf16* gB1 = a.W1t + (size_t)(bn + row0) * NN + col0;
        const bf16* gB2 = a.W2t + (size_t)(bn + row0) * NN + col0;

        f32x4 acc1[4][4], acc2[4][4];
#pragma unroll
        for (int i = 0; i < 4; ++i)
#pragma unroll
            for (int j = 0; j < 4; ++j) {
                acc1[i][j] = (f32x4){0.f, 0.f, 0.f, 0.f};
                acc2[i][j] = (f32x4){0.f, 0.f, 0.f, 0.f};
            }

        auto issue = [&](bf16* As, bf16* B1, bf16* B2, int kt) {
            const int kof = kt * BK;
            async_copy16(&As[off0],           gA  + kof);
            async_copy16(&As[off0 + 64 * BK], gA  + (size_t)64 * NN + kof);
            async_copy16(&B1[off0],           gB1 + kof);
            async_copy16(&B1[off0 + 64 * BK], gB1 + (size_t)64 * NN + kof);
            async_copy16(&B2[off0],           gB2 + kof);
            async_copy16(&B2[off0 + 64 * BK], gB2 + (size_t)64 * NN + kof);
        };
        auto compute = [&](const bf16* As, const bf16* B1, const bf16* B2) {
            bf16x8 af[4], b1[4], b2[4];
#pragma unroll
            for (int i = 0; i < 4; ++i)
                af[i] = *(const bf16x8*)&As[(wm + i * 16 + lrow) * BK + qe];
#pragma unroll
            for (int j = 0; j < 4; ++j) {
                b1[j] = *(const bf16x8*)&B1[(wn + j * 16 + lrow) * BK + qe];
                b2[j] = *(const bf16x8*)&B2[(wn + j * 16 + lrow) * BK + qe];
            }
#pragma unroll
            for (int i = 0; i < 4; ++i)
#pragma unroll
                for (int j = 0; j < 4; ++j) {
                    acc1[i][j] = __builtin_amdgcn_mfma_f32_16x16x32_bf16(
                        af[i], b1[j], acc1[i][j], 0, 0, 0);
                    acc2[i][j] = __builtin_amdgcn_mfma_f32_16x16x32_bf16(
                        af[i], b2[j], acc2[i][j], 0, 0, 0);
                }
        };

        issue(As0, B10, B20, 0);
#pragma unroll 1
        for (int kt = 0; kt < 62; kt += 2) {
            issue(As1, B11, B21, kt + 1); WAIT_VM(6); BAR();
            compute(As0, B10, B20); BAR();
            issue(As0, B10, B20, kt + 2); WAIT_VM(6); BAR();
            compute(As1, B11, B21); BAR();
        }
        issue(As1, B11, B21, 63); WAIT_VM(6); BAR();
        compute(As0, B10, B20); BAR();
        WAIT_VM(0); BAR();
        compute(As1, B11, B21);

        // epilogue: M1, M2(out), M1bf, B1bf
#pragma unroll
        for (int i = 0; i < 4; ++i)
#pragma unroll
            for (int j = 0; j < 4; ++j)
#pragma unroll
                for (int r = 0; r < 4; ++r) {
                    const size_t idx =
                        (size_t)(bm + wm + i * 16 + q * 4 + r) * NN +
                        (bn + wn + j * 16 + lrow);
                    const float v1 = acc1[i][j][r];
                    a.M1[idx]    = v1;
                    a.M2out[idx] = acc2[i][j][r];
                    const float w = a.W1[idx];
                    a.M1bf[idx] = (bf16)v1;
                    a.B1bf[idx] = (bf16)(v1 * w);
                }
    } else {
        const bf16* gA = a.W3bf + (size_t)(bm + row0) * NN + col0;
        const bf16* gB = a.W3t  + (size_t)(bn + row0) * NN + col0;

        f32x4 acc[4][4];
#pragma unroll
        for (int i = 0; i < 4; ++i)
#pragma unroll
            for (int j = 0; j < 4; ++j) acc[i][j] = (f32x4){0.f, 0.f, 0.f, 0.f};

        auto issue = [&](bf16* As, bf16* Bs, int kt) {
            const int kof = kt * BK;
            async_copy16(&As[off0],           gA + kof);
            async_copy16(&As[off0 + 64 * BK], gA + (size_t)64 * NN + kof);
            async_copy16(&Bs[off0],           gB + kof);
            async_copy16(&Bs[off0 + 64 * BK], gB + (size_t)64 * NN + kof);
        };
        auto compute = [&](const bf16* As, const bf16* Bs) {
            bf16x8 af[4], bfr[4];
#pragma unroll
            for (int i = 0; i < 4; ++i)
                af[i] = *(const bf16x8*)&As[(wm + i * 16 + lrow) * BK + qe];
#pragma unroll
            for (int j = 0; j < 4; ++j)
                bfr[j] = *(const bf16x8*)&Bs[(wn + j * 16 + lrow) * BK + qe];
#pragma unroll
            for (int i = 0; i < 4; ++i)
#pragma unroll
                for (int j = 0; j < 4; ++j)
                    acc[i][j] = __builtin_amdgcn_mfma_f32_16x16x32_bf16(
                        af[i], bfr[j], acc[i][j], 0, 0, 0);
        };

        issue(As0, B10, 0);
#pragma unroll 1
        for (int kt = 0; kt < 62; kt += 2) {
            issue(As1, B11, kt + 1); WAIT_VM(4); BAR();
            compute(As0, B10); BAR();
            issue(As0, B10, kt + 2); WAIT_VM(4); BAR();
            compute(As1, B11); BAR();
        }
        issue(As1, B11, 63); WAIT_VM(4); BAR();
        compute(As0, B10); BAR();
        WAIT_VM(0); BAR();
        compute(As1, B11);

#pragma unroll
        for (int i = 0; i < 4; ++i)
#pragma unroll
            for (int j = 0; j < 4; ++j)
#pragma unroll
                for (int r = 0; r < 4; ++r)
                    a.M3[(size_t)(bm + wm + i * 16 + q * 4 + r) * NN +
                         (bn + wn + j * 16 + lrow)] = acc[i][j][r];
    }
}

// ---------------------------------------------------------------------------
// Phase C: r0 gemm2 exact. 128x64 tile, depth-3, 4x1 waves.
// wg in [0,512): bm = (wg&15)*128, bn = (wg>>4)*64.
//   m5 = M1bf @ A,  m4 = B1bf @ A  (B operand = At rows), fused epilogue:
//   out = M1*M2 + M1 + M3 + M3*(m4*W1)*(M3 + m5)    (M2 resides in out)
// ---------------------------------------------------------------------------
__device__ __forceinline__ void gemm2_phase(const MegaArgs& a, char* smemraw,
                                            int wg) {
    bf16* A50 = (bf16*)smemraw;          // 4096 elems each
    bf16* A51 = A50 + 4096;
    bf16* A52 = A50 + 2 * 4096;
    bf16* A40 = A50 + 3 * 4096;
    bf16* A41 = A50 + 4 * 4096;
    bf16* A42 = A50 + 5 * 4096;
    bf16* Bs0 = A50 + 6 * 4096;          // 2048 elems each
    bf16* Bs1 = Bs0 + 2048;
    bf16* Bs2 = Bs0 + 2 * 2048;

    const int t  = threadIdx.x;
    const int bm = (wg & 15) * 128;
    const int bn = (wg >> 4) * 64;

    const int row0 = t >> 2;
    const int qp   = t & 3;
    const int col0 = ((qp ^ ((row0 >> 1) & 3)) << 3);
    const int off0 = t * 8;

    const bf16* g5 = a.M1bf + (size_t)(bm + row0) * NN + col0;
    const bf16* g4 = a.B1bf + (size_t)(bm + row0) * NN + col0;
    const bf16* gB = a.At   + (size_t)(bn + row0) * NN + col0;

    const int wave = t >> 6;
    const int lane = t & 63;
    const int wm   = wave * 32;          // 4x1 wave tiling
    const int lrow = lane & 15;
    const int q    = lane >> 4;
    const int qe   = (q ^ ((lrow >> 1) & 3)) << 3;

    f32x4 acc5[2][4], acc4[2][4];
#pragma unroll
    for (int i = 0; i < 2; ++i)
#pragma unroll
        for (int j = 0; j < 4; ++j) {
            acc5[i][j] = (f32x4){0.f, 0.f, 0.f, 0.f};
            acc4[i][j] = (f32x4){0.f, 0.f, 0.f, 0.f};
        }

    auto issue = [&](bf16* A5, bf16* A4, bf16* Bs, int kt) {
        const int kof = kt * BK;
        async_copy16(&A5[off0],           g5 + kof);
        async_copy16(&A5[off0 + 64 * BK], g5 + (size_t)64 * NN + kof);
        async_copy16(&A4[off0],           g4 + kof);
        async_copy16(&A4[off0 + 64 * BK], g4 + (size_t)64 * NN + kof);
        async_copy16(&Bs[off0],           gB + kof);
    };
    auto compute = [&](const bf16* A5, const bf16* A4, const bf16* Bs) {
        bf16x8 a5[2], a4[2], bfr[4];
#pragma unroll
        for (int i = 0; i < 2; ++i) {
            a5[i] = *(const bf16x8*)&A5[(wm + i * 16 + lrow) * BK + qe];
            a4[i] = *(const bf16x8*)&A4[(wm + i * 16 + lrow) * BK + qe];
        }
#pragma unroll
        for (int j = 0; j < 4; ++j)
            bfr[j] = *(const bf16x8*)&Bs[(j * 16 + lrow) * BK + qe];
#pragma unroll
        for (int i = 0; i < 2; ++i)
#pragma unroll
            for (int j = 0; j < 4; ++j) {
                acc5[i][j] = __builtin_amdgcn_mfma_f32_16x16x32_bf16(
                    a5[i], bfr[j], acc5[i][j], 0, 0, 0);
                acc4[i][j] = __builtin_amdgcn_mfma_f32_16x16x32_bf16(
                    a4[i], bfr[j], acc4[i][j], 0, 0, 0);
            }
    };

    issue(A50, A40, Bs0, 0);
    issue(A51, A41, Bs1, 1);
#pragma unroll 1
    for (int kt = 0; kt < 60; kt += 3) {
        issue(A52, A42, Bs2, kt + 2); WAIT_VM(10); BAR(); compute(A50, A40, Bs0); BAR();
        issue(A50, A40, Bs0, kt + 3); WAIT_VM(10); BAR(); compute(A51, A41, Bs1); BAR();
        issue(A51, A41, Bs1, kt + 4); WAIT_VM(10); BAR(); compute(A52, A42, Bs2); BAR();
    }
    issue(A52, A42, Bs2, 62); WAIT_VM(10); BAR(); compute(A50, A40, Bs0); BAR();
    issue(A50, A40, Bs0, 63); WAIT_VM(10); BAR(); compute(A51, A41, Bs1); BAR();
    WAIT_VM(5); BAR(); compute(A52, A42, Bs2); BAR();
    WAIT_VM(0); BAR(); compute(A50, A40, Bs0);

    // fused final epilogue: out = M1*M2 + M1 + M3 + M3*(m4*W1)*(M3 + m5)
#pragma unroll
    for (int i = 0; i < 2; ++i)
#pragma unroll
        for (int j = 0; j < 4; ++j)
#pragma unroll
            for (int r = 0; r < 4; ++r) {
                const size_t idx = (size_t)(bm + wm + i * 16 + q * 4 + r) * NN +
                                   (bn + j * 16 + lrow);
                const float m5 = acc5[i][j][r];
                const float m4 = acc4[i][j][r];
                const float m1 = a.M1[idx];
                const float m3 = a.M3[idx];
                const float w1 = a.W1[idx];
                const float m2 = a.out[idx];
                a.out[idx] = m1 * m2 + m1 + m3 + m3 * (m4 * w1) * (m3 + m5);
            }
}

// ---------------------------------------------------------------------------
// Cooperative mega kernel: cast -> grid.sync -> phase1 -> grid.sync -> gemm2.
// 512 blocks x 256 threads, 60 KiB LDS -> 2 blocks/CU, all co-resident.
// ---------------------------------------------------------------------------
__global__ __launch_bounds__(256, 2) void mega_kernel(MegaArgs a) {
    __shared__ __align__(16) char smem[61440];
    const int wg = blockIdx.x;

    // Phase A: 4096 cast tile-units over 512 blocks
#pragma unroll 1
    for (int u = 0; u < 8; ++u) {
        __syncthreads();
        cast_phase(a, smem, wg * 8 + u);
    }
    __threadfence();
    cg::this_grid().sync();

    phase1_phase(a, smem, wg);
    __threadfence();
    cg::this_grid().sync();

    gemm2_phase(a, smem, wg);
}

// Fallback standalone kernels (same device code, 3 dispatches)
__global__ __launch_bounds__(256) void cast_sa(MegaArgs a) {
    __shared__ __align__(16) char smem[64 * 65 * 4];
#pragma unroll 1
    for (int u = 0; u < 8; ++u) {
        __syncthreads();
        cast_phase(a, smem, blockIdx.x * 8 + u);
    }
}
__global__ __launch_bounds__(256, 2) void phase1_sa(MegaArgs a) {
    __shared__ __align__(16) char smem[6 * 4096 * 2];
    phase1_phase(a, smem, blockIdx.x);
}
__global__ __launch_bounds__(256, 2) void gemm2_sa(MegaArgs a) {
    __shared__ __align__(16) char smem[61440];
    gemm2_phase(a, smem, blockIdx.x);
}

// ---------------------------------------------------------------------------
extern "C" void kernel_launch(void* const* d_in, const int* in_sizes, int n_in,
                              void* d_out, int out_size, void* d_ws, size_t ws_size,
                              hipStream_t stream) {
    const float* A  = (const float*)d_in[0];
    const float* W1 = (const float*)d_in[1];
    const float* W2 = (const float*)d_in[2];
    const float* W3 = (const float*)d_in[3];
    float* out = (float*)d_out;

    const size_t P = (size_t)NN * NN;
    char* ws = (char*)d_ws;

    bf16* Abf  = (bf16*)ws;            // P*2 bytes each
    bf16* At   = Abf + P;
    bf16* W1t  = At + P;
    bf16* W2t  = W1t + P;
    bf16* W3bf = W2t + P;
    bf16* W3t  = W3bf + P;
    bf16* M1bf = W3t + P;
    bf16* B1bf = M1bf + P;
    float* M1  = (float*)(B1bf + P);   // P*4 bytes each
    float* M3  = M1 + P;
    // total: 8*2*P + 2*4*P = 24*P = 96 MiB

    MegaArgs ma;
    ma.cin[0] = A;  ma.coutT[0] = At;  ma.coutN[0] = Abf;
    ma.cin[1] = W1; ma.coutT[1] = W1t; ma.coutN[1] = nullptr;
    ma.cin[2] = W2; ma.coutT[2] = W2t; ma.coutN[2] = nullptr;
    ma.cin[3] = W3; ma.coutT[3] = W3t; ma.coutN[3] = W3bf;
    ma.Abf = Abf; ma.W1t = W1t; ma.W2t = W2t; ma.W3bf = W3bf; ma.W3t = W3t;
    ma.M1 = M1; ma.M2out = out; ma.M3 = M3;
    ma.W1 = W1; ma.M1bf = M1bf; ma.B1bf = B1bf;
    ma.At = At; ma.out = out;

    void* params[] = {(void*)&ma};
    hipError_t err = hipLaunchCooperativeKernel(
        (const void*)mega_kernel, dim3(512), dim3(256), params, 0, stream);
    if (err != hipSuccess) {
        (void)hipGetLastError();  // clear error state, use 3-dispatch fallback
        cast_sa<<<dim3(512), 256, 0, stream>>>(ma);
        phase1_sa<<<dim3(512), 256, 0, stream>>>(ma);
        gemm2_sa<<<dim3(512), 256, 0, stream>>>(ma);
    }
}

// Round 7
// 234.704 us; speedup vs baseline: 2.1647x; 2.1647x over previous
//
#include <hip/hip_runtime.h>
#include <hip/hip_bf16.h>
#include <stdint.h>

#define NN 2048
#define BK 32

typedef __bf16 bf16;
typedef __bf16 bf16x8 __attribute__((ext_vector_type(8)));
typedef __bf16 bf16x4 __attribute__((ext_vector_type(4)));
typedef float f32x4 __attribute__((ext_vector_type(4)));

// async global->LDS, 16B per lane (LDS dest = wave-uniform base + lane*16)
__device__ __forceinline__ void async_copy16(bf16* lds, const bf16* g) {
    __builtin_amdgcn_global_load_lds(
        (const __attribute__((address_space(1))) unsigned int*)g,
        (__attribute__((address_space(3))) unsigned int*)lds,
        16, 0, 0);
}

// fine-grained waits + compiler-visible barrier.
#define WAIT_VM(n) asm volatile("s_waitcnt vmcnt(" #n ")" ::: "memory")
#define BAR()                                  \
    do {                                       \
        asm volatile("" ::: "memory");         \
        __builtin_amdgcn_s_barrier();          \
        asm volatile("" ::: "memory");         \
    } while (0)

// ---------------------------------------------------------------------------
// fp32 -> bf16 transpose cast, z-batched. 64x64 tile, 256 threads. (r0 exact)
// ---------------------------------------------------------------------------
struct CastArgs {
    const float* in[4];
    bf16*        outT[4];
    bf16*        outN[4];
};

__global__ __launch_bounds__(256) void transpose_cast_kernel(CastArgs args) {
    const float* __restrict__ in = args.in[blockIdx.z];
    bf16* __restrict__ outT      = args.outT[blockIdx.z];
    bf16* __restrict__ outN      = args.outN[blockIdx.z];
    __shared__ float tile[64][65];
    const int bx = blockIdx.x * 64;   // col base
    const int by = blockIdx.y * 64;   // row base
    const int t  = threadIdx.x;
    const int c4 = (t & 15) * 4, r0 = t >> 4;
#pragma unroll
    for (int p = 0; p < 4; ++p) {
        const int r = r0 + p * 16;
        const float4 v = *(const float4*)&in[(size_t)(by + r) * NN + bx + c4];
        tile[r][c4 + 0] = v.x; tile[r][c4 + 1] = v.y;
        tile[r][c4 + 2] = v.z; tile[r][c4 + 3] = v.w;
        if (outN) {
            bf16x4 b = {(bf16)v.x, (bf16)v.y, (bf16)v.z, (bf16)v.w};
            *(bf16x4*)&outN[(size_t)(by + r) * NN + bx + c4] = b;
        }
    }
    __syncthreads();
    // outT[(bx+rw)][by+cc8 .. +7] = in[by+cc8+i][bx+rw] = tile[cc8+i][rw]
    const int cc8 = (t & 7) * 8, rw0 = t >> 3;
#pragma unroll
    for (int p = 0; p < 2; ++p) {
        const int rw = rw0 + p * 32;
        bf16x8 b;
#pragma unroll
        for (int i = 0; i < 8; ++i) b[i] = (bf16)tile[cc8 + i][rw];
        *(bf16x8*)&outT[(size_t)(bx + rw) * NN + by + cc8] = b;
    }
}

// ---------------------------------------------------------------------------
// Phase 1 (r0 exact): z=0 -> DUAL GEMM sharing A:  M1 = A@W1, M2(out) = A@W2
// for one 128x128 tile, plus fused emission of M1bf = bf16(M1),
// B1bf = bf16(M1*W1).  z=1 -> M3 = W3@W3 plain.
// Depth-2 double buffer (48 KB LDS), XOR-swizzled columns, vmcnt pipeline.
// ---------------------------------------------------------------------------
struct P1Args {
    const bf16*  Abf;
    const bf16*  W1t;
    const bf16*  W2t;
    const bf16*  W3bf;
    const bf16*  W3t;
    float*       M1;
    float*       M2out;
    float*       M3;
    const float* W1;
    bf16*        M1bf;
    bf16*        B1bf;
};

__global__ __launch_bounds__(256, 2) void phase1_kernel(P1Args a) {
    __shared__ bf16 As0[128 * BK], As1[128 * BK];
    __shared__ bf16 B10[128 * BK], B11[128 * BK];
    __shared__ bf16 B20[128 * BK], B21[128 * BK];

    const int t  = threadIdx.x;
    const int bm = blockIdx.x * 128;
    const int bn = blockIdx.y * 128;

    const int row0 = t >> 2;
    const int qp   = t & 3;
    const int col0 = ((qp ^ ((row0 >> 1) & 3)) << 3);  // XOR swizzle
    const int off0 = t * 8;

    const int wave = t >> 6;
    const int lane = t & 63;
    const int wm   = (wave >> 1) * 64;
    const int wn   = (wave & 1) * 64;
    const int lrow = lane & 15;
    const int q    = lane >> 4;
    const int qe   = (q ^ ((lrow >> 1) & 3)) << 3;

    if (blockIdx.z == 0) {
        const bf16* gA  = a.Abf + (size_t)(bm + row0) * NN + col0;
        const bf16* gB1 = a.W1t + (size_t)(bn + row0) * NN + col0;
        const bf16* gB2 = a.W2t + (size_t)(bn + row0) * NN + col0;

        f32x4 acc1[4][4], acc2[4][4];
#pragma unroll
        for (int i = 0; i < 4; ++i)
#pragma unroll
            for (int j = 0; j < 4; ++j) {
                acc1[i][j] = (f32x4){0.f, 0.f, 0.f, 0.f};
                acc2[i][j] = (f32x4){0.f, 0.f, 0.f, 0.f};
            }

        auto issue = [&](bf16* As, bf16* B1, bf16* B2, int kt) {
            const int kof = kt * BK;
            async_copy16(&As[off0],           gA  + kof);
            async_copy16(&As[off0 + 64 * BK], gA  + (size_t)64 * NN + kof);
            async_copy16(&B1[off0],           gB1 + kof);
            async_copy16(&B1[off0 + 64 * BK], gB1 + (size_t)64 * NN + kof);
            async_copy16(&B2[off0],           gB2 + kof);
            async_copy16(&B2[off0 + 64 * BK], gB2 + (size_t)64 * NN + kof);
        };
        auto compute = [&](const bf16* As, const bf16* B1, const bf16* B2) {
            bf16x8 af[4], b1[4], b2[4];
#pragma unroll
            for (int i = 0; i < 4; ++i)
                af[i] = *(const bf16x8*)&As[(wm + i * 16 + lrow) * BK + qe];
#pragma unroll
            for (int j = 0; j < 4; ++j) {
                b1[j] = *(const bf16x8*)&B1[(wn + j * 16 + lrow) * BK + qe];
                b2[j] = *(const bf16x8*)&B2[(wn + j * 16 + lrow) * BK + qe];
            }
#pragma unroll
            for (int i = 0; i < 4; ++i)
#pragma unroll
                for (int j = 0; j < 4; ++j) {
                    acc1[i][j] = __builtin_amdgcn_mfma_f32_16x16x32_bf16(
                        af[i], b1[j], acc1[i][j], 0, 0, 0);
                    acc2[i][j] = __builtin_amdgcn_mfma_f32_16x16x32_bf16(
                        af[i], b2[j], acc2[i][j], 0, 0, 0);
                }
        };

        issue(As0, B10, B20, 0);
#pragma unroll 1
        for (int kt = 0; kt < 62; kt += 2) {
            issue(As1, B11, B21, kt + 1); WAIT_VM(6); BAR();
            compute(As0, B10, B20); BAR();
            issue(As0, B10, B20, kt + 2); WAIT_VM(6); BAR();
            compute(As1, B11, B21); BAR();
        }
        issue(As1, B11, B21, 63); WAIT_VM(6); BAR();
        compute(As0, B10, B20); BAR();
        WAIT_VM(0); BAR();
        compute(As1, B11, B21);

        // epilogue: M1, M2(out), M1bf, B1bf
#pragma unroll
        for (int i = 0; i < 4; ++i)
#pragma unroll
            for (int j = 0; j < 4; ++j)
#pragma unroll
                for (int r = 0; r < 4; ++r) {
                    const size_t idx =
                        (size_t)(bm + wm + i * 16 + q * 4 + r) * NN +
                        (bn + wn + j * 16 + lrow);
                    const float v1 = acc1[i][j][r];
                    a.M1[idx]    = v1;
                    a.M2out[idx] = acc2[i][j][r];
                    const float w = a.W1[idx];
                    a.M1bf[idx] = (bf16)v1;
                    a.B1bf[idx] = (bf16)(v1 * w);
                }
    } else {
        const bf16* gA = a.W3bf + (size_t)(bm + row0) * NN + col0;
        const bf16* gB = a.W3t  + (size_t)(bn + row0) * NN + col0;

        f32x4 acc[4][4];
#pragma unroll
        for (int i = 0; i < 4; ++i)
#pragma unroll
            for (int j = 0; j < 4; ++j) acc[i][j] = (f32x4){0.f, 0.f, 0.f, 0.f};

        auto issue = [&](bf16* As, bf16* Bs, int kt) {
            const int kof = kt * BK;
            async_copy16(&As[off0],           gA + kof);
            async_copy16(&As[off0 + 64 * BK], gA + (size_t)64 * NN + kof);
            async_copy16(&Bs[off0],           gB + kof);
            async_copy16(&Bs[off0 + 64 * BK], gB + (size_t)64 * NN + kof);
        };
        auto compute = [&](const bf16* As, const bf16* Bs) {
            bf16x8 af[4], bfr[4];
#pragma unroll
            for (int i = 0; i < 4; ++i)
                af[i] = *(const bf16x8*)&As[(wm + i * 16 + lrow) * BK + qe];
#pragma unroll
            for (int j = 0; j < 4; ++j)
                bfr[j] = *(const bf16x8*)&Bs[(wn + j * 16 + lrow) * BK + qe];
#pragma unroll
            for (int i = 0; i < 4; ++i)
#pragma unroll
                for (int j = 0; j < 4; ++j)
                    acc[i][j] = __builtin_amdgcn_mfma_f32_16x16x32_bf16(
                        af[i], bfr[j], acc[i][j], 0, 0, 0);
        };

        issue(As0, B10, 0);
#pragma unroll 1
        for (int kt = 0; kt < 62; kt += 2) {
            issue(As1, B11, kt + 1); WAIT_VM(4); BAR();
            compute(As0, B10); BAR();
            issue(As0, B10, kt + 2); WAIT_VM(4); BAR();
            compute(As1, B11); BAR();
        }
        issue(As1, B11, 63); WAIT_VM(4); BAR();
        compute(As0, B10); BAR();
        WAIT_VM(0); BAR();
        compute(As1, B11);

#pragma unroll
        for (int i = 0; i < 4; ++i)
#pragma unroll
            for (int j = 0; j < 4; ++j)
#pragma unroll
                for (int r = 0; r < 4; ++r)
                    a.M3[(size_t)(bm + wm + i * 16 + q * 4 + r) * NN +
                         (bn + wn + j * 16 + lrow)] = acc[i][j][r];
    }
}

// ---------------------------------------------------------------------------
// Phase 2: fused dual GEMM + final epilogue. 128x64 tile, K-step 64 as TWO
// phase1-style 128x32 sub-tiles per buffer (address math byte-identical to
// proven code). Depth-2, CONSERVATIVE sync: issue(next) -> vmcnt(0) -> BAR ->
// compute(cur) -> BAR. Zero race surface; drain covered by co-resident block.
// 32 iterations -> half the barrier pairs of BK=32.
// LDS: 2 bufs x (16+16+8) KiB = 80 KiB -> 2 blocks/CU.
//   m5 = M1bf @ A,  m4 = B1bf @ A   (A given as At = A^T), shared B frags;
//   out = M1*M2 + M1 + M3 + M3*(m4*W1)*(M3 + m5)    (M2 resides in out)
// ---------------------------------------------------------------------------
struct Gemm2Args {
    const bf16*  M1bf;
    const bf16*  B1bf;
    const bf16*  At;
    const float* M1;
    const float* M3;
    const float* W1;
    float*       out;
};

__global__ __launch_bounds__(256, 2) void gemm2_fused_kernel(Gemm2Args args) {
    __shared__ bf16 A5b[2][2 * 128 * BK];  // [buf][sub*4096 + off] (M1bf)
    __shared__ bf16 A4b[2][2 * 128 * BK];  // (B1bf)
    __shared__ bf16 Bsb[2][2 * 64 * BK];   // (At)

    const int t  = threadIdx.x;
    const int bm = blockIdx.x * 128;
    const int bn = blockIdx.y * 64;

    const int row0 = t >> 2;
    const int qp   = t & 3;
    const int col0 = ((qp ^ ((row0 >> 1) & 3)) << 3);  // phase1 swizzle exact
    const int off0 = t * 8;

    const bf16* g5 = args.M1bf + (size_t)(bm + row0) * NN + col0;
    const bf16* g4 = args.B1bf + (size_t)(bm + row0) * NN + col0;
    const bf16* gB = args.At   + (size_t)(bn + row0) * NN + col0;

    const int wave = t >> 6;
    const int lane = t & 63;
    const int wm   = wave * 32;          // 4x1 wave tiling
    const int lrow = lane & 15;
    const int q    = lane >> 4;
    const int qe   = (q ^ ((lrow >> 1) & 3)) << 3;

    f32x4 acc5[2][4], acc4[2][4];
#pragma unroll
    for (int i = 0; i < 2; ++i)
#pragma unroll
        for (int j = 0; j < 4; ++j) {
            acc5[i][j] = (f32x4){0.f, 0.f, 0.f, 0.f};
            acc4[i][j] = (f32x4){0.f, 0.f, 0.f, 0.f};
        }

    auto issue = [&](int buf, int kt) {  // 10 copies: 2 sub-tiles x 5
#pragma unroll
        for (int s = 0; s < 2; ++s) {
            const int kof = kt * 64 + s * 32;
            bf16* A5 = &A5b[buf][s * 128 * BK];
            bf16* A4 = &A4b[buf][s * 128 * BK];
            bf16* Bs = &Bsb[buf][s * 64 * BK];
            async_copy16(&A5[off0],           g5 + kof);
            async_copy16(&A5[off0 + 64 * BK], g5 + (size_t)64 * NN + kof);
            async_copy16(&A4[off0],           g4 + kof);
            async_copy16(&A4[off0 + 64 * BK], g4 + (size_t)64 * NN + kof);
            async_copy16(&Bs[off0],           gB + kof);
        }
    };
    auto compute = [&](int buf) {
#pragma unroll
        for (int s = 0; s < 2; ++s) {
            const bf16* A5 = &A5b[buf][s * 128 * BK];
            const bf16* A4 = &A4b[buf][s * 128 * BK];
            const bf16* Bs = &Bsb[buf][s * 64 * BK];
            bf16x8 a5[2], a4[2], bfr[4];
#pragma unroll
            for (int i = 0; i < 2; ++i) {
                a5[i] = *(const bf16x8*)&A5[(wm + i * 16 + lrow) * BK + qe];
                a4[i] = *(const bf16x8*)&A4[(wm + i * 16 + lrow) * BK + qe];
            }
#pragma unroll
            for (int j = 0; j < 4; ++j)
                bfr[j] = *(const bf16x8*)&Bs[(j * 16 + lrow) * BK + qe];
#pragma unroll
            for (int i = 0; i < 2; ++i)
#pragma unroll
                for (int j = 0; j < 4; ++j) {
                    acc5[i][j] = __builtin_amdgcn_mfma_f32_16x16x32_bf16(
                        a5[i], bfr[j], acc5[i][j], 0, 0, 0);
                    acc4[i][j] = __builtin_amdgcn_mfma_f32_16x16x32_bf16(
                        a4[i], bfr[j], acc4[i][j], 0, 0, 0);
                }
        }
    };

    issue(0, 0);
#pragma unroll 1
    for (int kt = 0; kt < 31; ++kt) {
        issue((kt + 1) & 1, kt + 1);
        WAIT_VM(0); BAR();       // everything landed; zero liveness risk
        compute(kt & 1);
        BAR();
    }
    WAIT_VM(0); BAR();
    compute(1);                  // tile 31

    // fused final epilogue: out = M1*M2 + M1 + M3 + M3*(m4*W1)*(M3 + m5)
#pragma unroll
    for (int i = 0; i < 2; ++i)
#pragma unroll
        for (int j = 0; j < 4; ++j)
#pragma unroll
            for (int r = 0; r < 4; ++r) {
                const size_t idx = (size_t)(bm + wm + i * 16 + q * 4 + r) * NN +
                                   (bn + j * 16 + lrow);
                const float m5 = acc5[i][j][r];
                const float m4 = acc4[i][j][r];
                const float m1 = args.M1[idx];
                const float m3 = args.M3[idx];
                const float w1 = args.W1[idx];
                const float m2 = args.out[idx];
                args.out[idx] =
                    m1 * m2 + m1 + m3 + m3 * (m4 * w1) * (m3 + m5);
            }
}

// ---------------------------------------------------------------------------
extern "C" void kernel_launch(void* const* d_in, const int* in_sizes, int n_in,
                              void* d_out, int out_size, void* d_ws, size_t ws_size,
                              hipStream_t stream) {
    const float* A  = (const float*)d_in[0];
    const float* W1 = (const float*)d_in[1];
    const float* W2 = (const float*)d_in[2];
    const float* W3 = (const float*)d_in[3];
    float* out = (float*)d_out;

    const size_t P = (size_t)NN * NN;
    char* ws = (char*)d_ws;

    bf16* Abf  = (bf16*)ws;            // P*2 bytes each
    bf16* At   = Abf + P;
    bf16* W1t  = At + P;
    bf16* W2t  = W1t + P;
    bf16* W3bf = W2t + P;
    bf16* W3t  = W3bf + P;
    bf16* M1bf = W3t + P;
    bf16* B1bf = M1bf + P;
    float* M1  = (float*)(B1bf + P);   // P*4 bytes each
    float* M3  = M1 + P;
    // total: 8*2*P + 2*4*P = 24*P = 96 MiB

    CastArgs ca;
    ca.in[0] = A;  ca.outT[0] = At;  ca.outN[0] = Abf;
    ca.in[1] = W1; ca.outT[1] = W1t; ca.outN[1] = nullptr;
    ca.in[2] = W2; ca.outT[2] = W2t; ca.outN[2] = nullptr;
    ca.in[3] = W3; ca.outT[3] = W3t; ca.outN[3] = W3bf;
    transpose_cast_kernel<<<dim3(NN / 64, NN / 64, 4), 256, 0, stream>>>(ca);

    // phase 1: z=0 dual (M1 = A@W1, M2 = A@W2, + M1bf/B1bf), z=1 M3 = W3@W3
    P1Args p1;
    p1.Abf = Abf; p1.W1t = W1t; p1.W2t = W2t; p1.W3bf = W3bf; p1.W3t = W3t;
    p1.M1 = M1; p1.M2out = out; p1.M3 = M3;
    p1.W1 = W1; p1.M1bf = M1bf; p1.B1bf = B1bf;
    phase1_kernel<<<dim3(NN / 128, NN / 128, 2), 256, 0, stream>>>(p1);

    // phase 2: fused dual GEMM (m5 = M1bf@A, m4 = (M1*W1)@A) + final epilogue
    Gemm2Args g2;
    g2.M1bf = M1bf; g2.B1bf = B1bf; g2.At = At;
    g2.M1 = M1; g2.M3 = M3; g2.W1 = W1; g2.out = out;
    gemm2_fused_kernel<<<dim3(NN / 128, NN / 64), 256, 0, stream>>>(g2);
}